// Round 7
// baseline (907.323 us; speedup 1.0000x reference)
//
#include <hip/hip_runtime.h>
#include <stdint.h>

#define B_SZ 4096
#define OBS 256
#define ACT 64
#define HID 1024
#define NOPT 8

typedef __attribute__((ext_vector_type(8))) short short8;
typedef __attribute__((ext_vector_type(4))) float floatx4;
typedef __attribute__((ext_vector_type(4))) unsigned int u32x4;

// ---------------- workspace layout (byte offsets) ----------------
constexpr long long OFF_WT_I1 = 0;
constexpr long long OFF_WT_I2 = OFF_WT_I1 + 2LL*1024*256*2;
constexpr long long OFF_WT_T1 = OFF_WT_I2 + 2LL*1024*1024*2;
constexpr long long OFF_WT_T2 = OFF_WT_T1 + 2LL*1024*256*2;
constexpr long long OFF_WT_X1 = OFF_WT_T2 + 2LL*1024*1024*2;
constexpr long long OFF_WT_X2 = OFF_WT_X1 + 2LL*1024*384*2;
constexpr long long OFF_WT_P1 = OFF_WT_X2 + 2LL*1024*1024*2;
constexpr long long OFF_WT_P2 = OFF_WT_P1 + 8LL*1024*256*2;
constexpr long long OFF_WT_ML = OFF_WT_P2 + 8LL*1024*1024*2;
constexpr long long OFF_WT_B1 = OFF_WT_ML + 8LL*128*1024*2;
constexpr long long OFF_XQ    = OFF_WT_B1 + 8LL*1024*256*2;
constexpr long long OFF_NS    = OFF_XQ + 4096LL*384*2;
constexpr long long OFF_AGS   = OFF_NS + 4096LL*256*2;
constexpr long long OFF_AGN   = OFF_AGS + 4224LL*256*2;
constexpr long long OFF_HAX   = OFF_AGN + 4224LL*256*2;
constexpr long long OFF_HAI   = OFF_HAX + 2LL*4096*1024*2;
constexpr long long OFF_HAT   = OFF_HAI + 2LL*4096*1024*2;
constexpr long long OFF_HAP   = OFF_HAT + 2LL*4096*1024*2;
constexpr long long OFF_HAB   = OFF_HAP + 4224LL*1024*2;
constexpr long long OFF_HBP   = OFF_HAB + 4224LL*1024*2;
// partial-sum slices: qi [2z][8sl][4096], qon/qt [2z][8sl][4096][8]
constexpr long long OFF_QI    = OFF_HBP + 4224LL*1024*2;
constexpr long long OFF_QON   = OFF_QI + 2LL*8*4096*4;
constexpr long long OFF_QT    = OFF_QON + 2LL*8*4096*8*4;
// muls partials: [4 kchunk][4224][128] fp32
constexpr long long OFF_MULS  = OFF_QT + 2LL*8*4096*8*4;
constexpr long long MULS_CH   = 4224LL*128*4;                 // 2162688 bytes per chunk
constexpr long long OFF_PERM  = OFF_MULS + 4LL*MULS_CH;
constexpr long long OFF_OPTG  = OFF_PERM + 4096LL*4;
constexpr long long OFF_BP    = OFF_OPTG + ((4224LL*4 + 255) & ~255LL);
constexpr long long OFF_LOGP  = OFF_BP + 4096LL*4;
constexpr long long OFF_TILEB = OFF_LOGP + 4096LL*4;                   // 272*64
constexpr long long OFF_TILEC = OFF_TILEB + 272LL*64;                  // 232*64
constexpr long long OFF_TILED = OFF_TILEC + 232LL*64;                  // 160*64
constexpr long long WS_TOTAL  = OFF_TILED + 160LL*64;

struct Tile {
  long long aOff, wOff, cOff;
  int mStart, mEnd, K, nCols, flags, biasSel, biasOff, redSel, redOff, kLen;
};
struct Ptrs { const float* bias[9]; const float* w3[3]; };
struct TrSrcs { const float* p[11]; };

__device__ __forceinline__ unsigned short f2bf(float x){
  union { float f; unsigned u; } v; v.f = x;
  unsigned r = v.u + 0x7fffu + ((v.u >> 16) & 1u);
  return (unsigned short)(r >> 16);
}
__device__ __forceinline__ float bf2f(unsigned short h){
  union { float f; unsigned u; } v; v.u = ((unsigned)h) << 16; return v.f;
}

// ---------------- layer tables ----------------
__device__ const long long tr_ws[11] = {256*1024,1024*1024,256*1024,1024*1024,328*1024,1024*1024,256*1024,1024*1024,1024*64,1024*64,256*1024};
__device__ const long long tr_ts[11] = {1024*256,1024*1024,1024*256,1024*1024,1024*384,1024*1024,1024*256,1024*1024,128*1024,128*1024,1024*256};
__device__ const long long tr_dst[11] = {OFF_WT_I1,OFF_WT_I2,OFF_WT_T1,OFF_WT_T2,OFF_WT_X1,OFF_WT_X2,OFF_WT_P1,OFF_WT_P2,OFF_WT_ML,OFF_WT_ML+64LL*1024*2,OFF_WT_B1};

// ---------------- fast transpose: fp32 [K,N] -> bf16 [N,Kpad], 64x64 tiles ----------------
__device__ const int t2_cum[12] = {0,128,640,768,1280,1472,1984,2496,4544,4672,4800,5312};
__device__ const int t2_nk[11]  = {4,16,4,16,6,16,4,16,16,16,4};
__device__ const int t2_N[11]   = {1024,1024,1024,1024,1024,1024,1024,1024,64,64,1024};
__device__ const int t2_K[11]   = {256,1024,256,1024,328,1024,256,1024,1024,1024,256};
__device__ const int t2_Kp[11]  = {256,1024,256,1024,384,1024,256,1024,1024,1024,256};

__global__ __launch_bounds__(256)
void k_tr(char* __restrict__ wsB, TrSrcs srcs){
  __shared__ float lds[64*68];
  int id = blockIdx.x, j = 0;
  while (id >= t2_cum[j+1]) j++;
  int t = id - t2_cum[j];
  int nk = t2_nk[j], nn = t2_N[j] >> 6;
  int per = nk*nn;
  int z = t / per, r = t % per;
  int kt = r % nk, nt = r / nk;
  int K = t2_K[j], Kp = t2_Kp[j], N = t2_N[j];
  const float* src = srcs.p[j] + (long long)z * tr_ws[j];
  unsigned short* dst = (unsigned short*)(wsB + tr_dst[j]) + (long long)z * tr_ts[j];
  int k0 = kt*64, n0 = nt*64;
  int tid = threadIdx.x;
  int kl = tid >> 2, nc = tid & 3;
  int krow = k0 + kl;
  const float* s = src + (long long)krow*N + n0 + nc*16;
  #pragma unroll
  for (int i=0;i<4;i++){
    float4 v = (krow < K) ? *(const float4*)(s + i*4) : make_float4(0.f,0.f,0.f,0.f);
    *(float4*)(&lds[kl*68 + nc*16 + i*4]) = v;
  }
  __syncthreads();
  int nl = tid >> 2, kc = tid & 3;
  unsigned int w[8];
  #pragma unroll
  for (int p=0;p<8;p++){
    float a = lds[(kc*16 + 2*p)*68 + nl];
    float b = lds[(kc*16 + 2*p + 1)*68 + nl];
    w[p] = (unsigned)f2bf(a) | ((unsigned)f2bf(b) << 16);
  }
  u32x4 o0 = {w[0],w[1],w[2],w[3]}, o1 = {w[4],w[5],w[6],w[7]};
  char* d = (char*)(dst + (long long)(n0+nl)*Kp + k0 + kc*16);
  *(u32x4*)d = o0; *(u32x4*)(d + 16) = o1;
}

// ---------------- routing + all tile tables ----------------
__global__ void k_route(char* __restrict__ wsB, const int* __restrict__ option,
                        float* __restrict__ out){
  __shared__ int cnt[NOPT], off[NOPT+1], cur[NOPT], ctiles[NOPT], toff[NOPT+1];
  int tid = threadIdx.x;
  int* perm = (int*)(wsB + OFF_PERM);
  int* optg = (int*)(wsB + OFF_OPTG);
  Tile* tb = (Tile*)(wsB + OFF_TILEB);
  Tile* tc = (Tile*)(wsB + OFF_TILEC);
  Tile* tdt = (Tile*)(wsB + OFF_TILED);
  if (tid < NOPT) cnt[tid] = 0;
  __syncthreads();
  for (int b = tid; b < B_SZ; b += 256) atomicAdd(&cnt[option[b]], 1);
  __syncthreads();
  if (tid == 0){
    off[0] = 0; toff[0] = 0;
    for (int o=0;o<NOPT;o++){
      off[o+1] = off[o] + cnt[o];
      ctiles[o] = (cnt[o] + 127) >> 7;
      toff[o+1] = toff[o] + ctiles[o];
      cur[o] = off[o];
    }
    out[0] = 0.f; out[1] = 0.f;
  }
  __syncthreads();
  for (int b = tid; b < B_SZ; b += 256){
    int o = option[b];
    int pos = atomicAdd(&cur[o], 1);
    perm[pos] = b; optg[pos] = o;
  }
  __syncthreads();
  // dense tiles (stage B and C): 6 tasks x 32 m-tiles
  if (tid < 192){
    int task = tid/32, mt = tid%32, z = task&1, net = task>>1;
    int ms = mt*128;
    Tile T{};
    T.mStart = ms; T.mEnd = 4096; T.nCols = 1024; T.flags = 0;
    T.redSel = 0; T.redOff = 0;
    if (net==0){ T.K=384; T.aOff = OFF_XQ + (long long)ms*768; T.wOff = OFF_WT_X1 + (long long)z*786432; T.cOff = OFF_HAX + (long long)z*8388608; T.biasSel=0; }
    else if (net==1){ T.K=256; T.aOff = OFF_NS + (long long)ms*512; T.wOff = OFF_WT_I1 + (long long)z*524288; T.cOff = OFF_HAI + (long long)z*8388608; T.biasSel=1; }
    else { T.K=256; T.aOff = OFF_NS + (long long)ms*512; T.wOff = OFF_WT_T1 + (long long)z*524288; T.cOff = OFF_HAT + (long long)z*8388608; T.biasSel=2; }
    T.biasOff = z*1024; T.kLen = T.K;
    tb[tid] = T;
    Tile C{};
    C.mStart = ms; C.mEnd = 4096; C.K = 1024; C.nCols = 1024; C.kLen = 1024;
    if (net==0){ C.flags=2; C.aOff = OFF_HAX + (long long)z*8388608 + (long long)ms*2048; C.wOff = OFF_WT_X2 + (long long)z*2097152; C.cOff = OFF_QI + (long long)z*131072; C.biasSel=5; C.redSel=0; C.redOff=z*1024; }
    else if (net==1){ C.flags=3; C.aOff = OFF_HAI + (long long)z*8388608 + (long long)ms*2048; C.wOff = OFF_WT_I2 + (long long)z*2097152; C.cOff = OFF_QON + (long long)z*1048576; C.biasSel=6; C.redSel=1; C.redOff=z*8192; }
    else { C.flags=3; C.aOff = OFF_HAT + (long long)z*8388608 + (long long)ms*2048; C.wOff = OFF_WT_T2 + (long long)z*2097152; C.cOff = OFF_QT + (long long)z*1048576; C.biasSel=7; C.redSel=2; C.redOff=z*8192; }
    C.biasOff = z*1024;
    tc[tid] = C;
  }
  // grouped tiles, thread per option
  if (tid < NOPT){
    int o = tid, base = toff[o], gs = off[o], ge = off[o+1];
    for (int t=0; t<ctiles[o]; t++){
      int ms = gs + t*128;
      Tile P{};
      P.mStart=ms; P.mEnd=ge; P.K=256; P.nCols=1024; P.flags=0; P.kLen=256;
      P.aOff = OFF_AGS + (long long)ms*512; P.wOff = OFF_WT_P1 + (long long)o*524288;
      P.cOff = OFF_HAP; P.biasSel=3; P.biasOff=o*1024;
      tb[192 + base + t] = P;
      Tile Bt{};
      Bt.mStart=ms; Bt.mEnd=ge; Bt.K=256; Bt.nCols=1024; Bt.flags=0; Bt.kLen=256;
      Bt.aOff = OFF_AGN + (long long)ms*512; Bt.wOff = OFF_WT_B1 + (long long)o*524288;
      Bt.cOff = OFF_HAB; Bt.biasSel=4; Bt.biasOff=o*1024;
      tb[232 + base + t] = Bt;
      Tile C2{};
      C2.mStart=ms; C2.mEnd=ge; C2.K=1024; C2.nCols=1024; C2.flags=0; C2.kLen=1024;
      C2.aOff = OFF_HAP + (long long)ms*2048; C2.wOff = OFF_WT_P2 + (long long)o*2097152;
      C2.cOff = OFF_HBP; C2.biasSel=8; C2.biasOff=o*1024;
      tc[192 + base + t] = C2;
      // mu/ls head GEMM: K split into 4 chunks of 256, partial outputs
      #pragma unroll
      for (int c=0;c<4;c++){
        Tile M{};
        M.mStart=ms; M.mEnd=ge; M.K=1024; M.nCols=128; M.flags=1; M.kLen=256;
        M.aOff = OFF_HBP + (long long)ms*2048 + c*512;
        M.wOff = OFF_WT_ML + (long long)o*262144 + c*512;
        M.cOff = OFF_MULS + (long long)c*MULS_CH;
        M.biasSel=-1;
        tdt[c*40 + base + t] = M;
      }
    }
  }
  __syncthreads();
  int tT = toff[NOPT];
  for (int s = tT + tid; s < 40; s += 256){
    tb[192+s].kLen = 0; tb[232+s].kLen = 0; tc[192+s].kLen = 0;
    tdt[s].kLen = 0; tdt[40+s].kLen = 0; tdt[80+s].kLen = 0; tdt[120+s].kLen = 0;
  }
}

// ---------------- prep: gather, xq build, ns convert ----------------
__global__ void k_prep(char* __restrict__ wsB, const float* __restrict__ state,
                       const float* __restrict__ action, const float* __restrict__ nstate,
                       const int* __restrict__ option){
  int blk = blockIdx.x, tid = threadIdx.x;
  const int* perm = (const int*)(wsB + OFF_PERM);
  if (blk < 4224){
    unsigned short* agS = (unsigned short*)(wsB + OFF_AGS);
    unsigned short* agN = (unsigned short*)(wsB + OFF_AGN);
    long long o = (long long)blk*256 + tid;
    if (blk < 4096){
      long long src = (long long)perm[blk]*256 + tid;
      agS[o] = f2bf(state[src]); agN[o] = f2bf(nstate[src]);
    } else { agS[o] = 0; agN[o] = 0; }
  } else if (blk < 8320){
    int b = blk - 4224;
    unsigned short* xq = (unsigned short*)(wsB + OFF_XQ);
    for (int c = tid; c < 384; c += 256){
      float v;
      if (c < 256) v = state[(long long)b*256 + c];
      else if (c < 320) v = action[(long long)b*64 + (c-256)];
      else if (c < 328) v = (option[b] == (c-320)) ? 1.f : 0.f;
      else v = 0.f;
      xq[(long long)b*384 + c] = f2bf(v);
    }
  } else {
    long long i = (long long)(blk-8320)*1024 + tid;
    unsigned short* nsb = (unsigned short*)(wsB + OFF_NS);
    #pragma unroll
    for (int k=0;k<4;k++){ nsb[i] = f2bf(nstate[i]); i += 256; }
  }
}

// ---------------- barrier-free per-wave GEMM: block 128x256, wave 64x128 ----------------
// No LDS, no __syncthreads. Each wave direct-loads its MFMA fragments from global
// (A[row][k+quad*8..+8] 16B, same layout the LDS path used) with 2-deep reg pipeline.
__global__ __launch_bounds__(256, 2)
void k_gemm(char* __restrict__ wsB, long long tileOff, Ptrs ptrs){
  int nx = gridDim.x, T = gridDim.y;
  int id = blockIdx.y*nx + blockIdx.x;
  int xb, yt;
  if ((T & 7) == 0){
    int xcd = id & 7, g = id >> 3;
    xb = g % nx; yt = (g / nx) * 8 + xcd;
  } else { xb = blockIdx.x; yt = blockIdx.y; }
  Tile t = ((const Tile*)(wsB + tileOff))[yt];
  if (t.kLen == 0) return;
  int n0 = xb * 256;
  if (n0 >= t.nCols) return;

  int tid = threadIdx.x;
  int wave = tid >> 6, lane = tid & 63;
  int wm = wave & 1, wn = wave >> 1;
  int quad = lane >> 4, l16 = lane & 15;
  int n0w = n0 + wn*128;

  const floatx4 fzero = {0.f,0.f,0.f,0.f};
  floatx4 acc[4][8];
  #pragma unroll
  for (int mi=0;mi<4;mi++)
    #pragma unroll
    for (int ni=0;ni<8;ni++) acc[mi][ni] = fzero;

  long long rowB = (long long)t.K*2;
  const char* Ab = wsB + t.aOff;
  const char* Bb = wsB + t.wOff;
  const char* pa[4]; const char* pb[8];
  #pragma unroll
  for (int mi=0;mi<4;mi++)
    pa[mi] = Ab + (long long)(wm*64 + mi*16 + l16)*rowB + quad*16;
  #pragma unroll
  for (int ni=0;ni<8;ni++)
    pb[ni] = Bb + (long long)(n0w + ni*16 + l16)*rowB + quad*16;

  #define LD(dA, dB, KO) { \
    _Pragma("unroll") for (int mi=0;mi<4;mi++) dA[mi] = *(const short8*)(pa[mi] + (KO)); \
    _Pragma("unroll") for (int ni=0;ni<8;ni++) dB[ni] = *(const short8*)(pb[ni] + (KO)); }
  #define MM(sA, sB) { \
    _Pragma("unroll") for (int mi=0;mi<4;mi++) \
      _Pragma("unroll") for (int ni=0;ni<8;ni++) \
        acc[mi][ni] = __builtin_amdgcn_mfma_f32_16x16x32_bf16(sA[mi], sB[ni], acc[mi][ni], 0, 0, 0); }

  int nkb = t.kLen >> 5;   // BK=32 per step; kLen is a multiple of 64 so nkb is even
  short8 aC[4], bC[8], aN[4], bN[8];
  LD(aC, bC, 0);
  LD(aN, bN, 64);
  for (int kb = 0; kb < nkb; kb += 2){
    long long ko = (long long)kb*64;
    MM(aC, bC);
    if (kb + 2 < nkb) LD(aC, bC, ko + 128);
    MM(aN, bN);
    if (kb + 3 < nkb) LD(aN, bN, ko + 192);
  }
  #undef LD
  #undef MM

  if (t.flags <= 1){
    const float* bz = (t.biasSel >= 0) ? (ptrs.bias[t.biasSel] + t.biasOff) : nullptr;
    #pragma unroll
    for (int ni=0;ni<8;ni++){
      int col = n0w + ni*16 + l16;
      if (col >= t.nCols) continue;
      float bval = bz ? bz[col] : 0.f;
      #pragma unroll
      for (int mi=0;mi<4;mi++){
        int rbase = t.mStart + wm*64 + mi*16 + quad*4;
        floatx4 v = acc[mi][ni];
        #pragma unroll
        for (int r=0;r<4;r++){
          int grow = rbase + r;
          if (grow < t.mEnd){
            float x = v[r] + bval;
            if (t.flags == 0){
              x = fmaxf(x, 0.f);
              ((unsigned short*)(wsB + t.cOff))[(long long)grow*t.nCols + col] = f2bf(x);
            } else {
              ((float*)(wsB + t.cOff))[(long long)grow*t.nCols + col] = x;
            }
          }
        }
      }
    }
  } else {
    // fused head, partial-sum slice per (n-block, wn): no atomics. slices 0..7
    int NC = (t.flags == 2) ? 1 : 8;
    const float* w3 = ptrs.w3[t.redSel] + t.redOff;
    const float* bz = ptrs.bias[t.biasSel] + t.biasOff;
    int sl = xb*2 + wn;  // 0..7
    float* red = (float*)(wsB + t.cOff) + (long long)sl*4096*NC;
    float bv[8]; int colv[8];
    #pragma unroll
    for (int ni=0;ni<8;ni++){ colv[ni] = n0w + ni*16 + l16; bv[ni] = bz[colv[ni]]; }
    #pragma unroll
    for (int mi=0;mi<4;mi++){
      #pragma unroll
      for (int r=0;r<4;r++){
        int row = t.mStart + wm*64 + mi*16 + quad*4 + r;
        float v[8];
        #pragma unroll
        for (int c=0;c<8;c++) v[c] = 0.f;
        #pragma unroll
        for (int ni=0;ni<8;ni++){
          float x = fmaxf(acc[mi][ni][r] + bv[ni], 0.f);
          if (NC == 1) v[0] += x * w3[colv[ni]];
          else {
            #pragma unroll
            for (int c=0;c<8;c++) v[c] += x * w3[colv[ni]*8 + c];
          }
        }
        for (int c=0;c<NC;c++){
          float s = v[c];
          s += __shfl_xor(s,1); s += __shfl_xor(s,2); s += __shfl_xor(s,4); s += __shfl_xor(s,8);
          if (l16 == 0 && row < t.mEnd) red[(long long)row*NC + c] = s;
        }
      }
    }
  }
}

// ---------------- fused beta head + policy epilogue (4 jobs/block) ----------------
__global__ void k_bp(char* __restrict__ wsB, const float* __restrict__ noise,
                     const float* __restrict__ bmu, const float* __restrict__ bls,
                     const float* __restrict__ beW2, const float* __restrict__ beb2,
                     float* __restrict__ out){
  int job = blockIdx.x*4 + (threadIdx.x >> 6);
  int lane = threadIdx.x & 63;
  const int* perm = (const int*)(wsB + OFF_PERM);
  const int* optg = (const int*)(wsB + OFF_OPTG);
  if (job < B_SZ){
    int i = job, o = optg[i], b = perm[i];
    const float* muls = (const float*)(wsB + OFF_MULS);
    float* logp = (float*)(wsB + OFF_LOGP);
    float mu = bmu[o*ACT + lane];
    float ls = bls[o*ACT + lane];
    #pragma unroll
    for (int c=0;c<4;c++){
      mu += muls[(long long)c*(MULS_CH/4) + (long long)i*128 + lane];
      ls += muls[(long long)c*(MULS_CH/4) + (long long)i*128 + 64 + lane];
    }
    ls = fminf(fmaxf(ls, -20.f), 2.f);
    float nv = noise[(long long)b*ACT + lane];
    float pre = mu + expf(ls)*nv;
    out[2 + (long long)b*ACT + lane] = tanhf(pre);
    float xx = -2.f*pre;
    float sp = fmaxf(xx, 0.f) + log1pf(expf(-fabsf(xx)));
    const float LOG2PI = 1.8378770664093453f;
    const float LN2 = 0.6931471805599453f;
    float lp = -0.5f*nv*nv - ls - 0.5f*LOG2PI - 2.f*(LN2 - pre - sp);
    for (int s=32;s;s>>=1) lp += __shfl_xor(lp, s);
    if (lane == 0){ out[2 + (long long)B_SZ*ACT + b] = lp; logp[b] = lp; }
  } else {
    int i = job - B_SZ, o = optg[i], b = perm[i];
    const char* hrow = wsB + OFF_HAB + (long long)i*2048;
    const float* w = beW2 + (long long)o*HID;
    float* bp = (float*)(wsB + OFF_BP);
    short8 v0 = *(const short8*)(hrow + lane*16);
    short8 v1 = *(const short8*)(hrow + 1024 + lane*16);
    float acc = 0.f;
    #pragma unroll
    for (int e=0;e<8;e++){
      acc += bf2f((unsigned short)v0[e]) * w[lane*8 + e];
      acc += bf2f((unsigned short)v1[e]) * w[512 + lane*8 + e];
    }
    for (int s=32;s;s>>=1) acc += __shfl_xor(acc, s);
    if (lane == 0){
      float v = 1.f/(1.f + expf(-(acc + beb2[o])));
      out[2 + (long long)B_SZ*ACT + B_SZ + b] = v; bp[b] = v;
    }
  }
}

// ---------------- TD target + losses (reduces 8 partial slices) ----------------
__global__ void k_td(const char* __restrict__ wsB, const int* __restrict__ option,
                     const float* __restrict__ reward, const float* __restrict__ done,
                     const float* __restrict__ xb3, const float* __restrict__ ib3,
                     const float* __restrict__ tb3, float* __restrict__ out){
  int b = blockIdx.x*256 + threadIdx.x;
  const float* qiP  = (const float*)(wsB + OFF_QI);
  const float* qonP = (const float*)(wsB + OFF_QON);
  const float* qtP  = (const float*)(wsB + OFF_QT);
  const float* bp   = (const float*)(wsB + OFF_BP);
  const float* logp = (const float*)(wsB + OFF_LOGP);
  float q1 = xb3[0], q2 = xb3[1];
  #pragma unroll
  for (int sl=0; sl<8; sl++){
    q1 += qiP[sl*4096 + b];
    q2 += qiP[32768 + sl*4096 + b];
  }
  float qons[2][8], qts[2][8];
  #pragma unroll
  for (int z=0;z<2;z++)
    #pragma unroll
    for (int o=0;o<8;o++){ qons[z][o] = ib3[z*8+o]; qts[z][o] = tb3[z*8+o]; }
  for (int z=0;z<2;z++){
    for (int sl=0; sl<8; sl++){
      long long base = ((long long)(z*8 + sl)*4096 + b)*8;
      #pragma unroll
      for (int o=0;o<8;o++){ qons[z][o] += qonP[base+o]; qts[z][o] += qtP[base+o]; }
    }
  }
  float qitv[NOPT];
  #pragma unroll
  for (int o=0;o<NOPT;o++) qitv[o] = fminf(qts[0][o], qts[1][o]);
  float qcur = qitv[option[b]];
  float best = -1e30f; int bo = 0;
  #pragma unroll
  for (int o=0;o<NOPT;o++){
    float v = fminf(qons[0][o], qons[1][o]);
    if (v > best){ best = v; bo = o; }
  }
  float qnext = qitv[bo];
  float bpv = bp[b];
  float backup = reward[b] + 0.99f*(1.f - done[b])*((1.f - bpv)*qcur + bpv*qnext);
  float d1 = q1 - backup, d2 = q2 - backup;
  float tq = d1*d1 + d2*d2;
  float qpi = fminf(q1, q2);
  float tp = 0.2f*logp[b] - qpi;
  for (int s=32;s;s>>=1){ tq += __shfl_xor(tq, s); tp += __shfl_xor(tp, s); }
  __shared__ float sq[4], sp2[4];
  int wave = threadIdx.x>>6, lane = threadIdx.x&63;
  if (lane==0){ sq[wave]=tq; sp2[wave]=tp; }
  __syncthreads();
  if (threadIdx.x==0){
    atomicAdd(&out[0], (sq[0]+sq[1]+sq[2]+sq[3])/(float)B_SZ);
    atomicAdd(&out[1], (sp2[0]+sp2[1]+sp2[2]+sp2[3])/(float)B_SZ);
  }
}

extern "C" void kernel_launch(void* const* d_in, const int* in_sizes, int n_in,
                              void* d_out, int out_size, void* d_ws, size_t ws_size,
                              hipStream_t stream){
  const float* state  = (const float*)d_in[0];
  const float* action = (const float*)d_in[1];
  const float* nstate = (const float*)d_in[2];
  const float* reward = (const float*)d_in[3];
  const float* done   = (const float*)d_in[4];
  const float* noise  = (const float*)d_in[5];
  const int*   option = (const int*)d_in[6];
  const float* iq_W1 = (const float*)d_in[7];  const float* iq_b1 = (const float*)d_in[8];
  const float* iq_W2 = (const float*)d_in[9];  const float* iq_b2 = (const float*)d_in[10];
  const float* iq_W3 = (const float*)d_in[11]; const float* iq_b3 = (const float*)d_in[12];
  const float* tq_W1 = (const float*)d_in[13]; const float* tq_b1 = (const float*)d_in[14];
  const float* tq_W2 = (const float*)d_in[15]; const float* tq_b2 = (const float*)d_in[16];
  const float* tq_W3 = (const float*)d_in[17]; const float* tq_b3 = (const float*)d_in[18];
  const float* xw_W1 = (const float*)d_in[19]; const float* xw_b1 = (const float*)d_in[20];
  const float* xw_W2 = (const float*)d_in[21]; const float* xw_b2 = (const float*)d_in[22];
  const float* xw_W3 = (const float*)d_in[23]; const float* xw_b3 = (const float*)d_in[24];
  const float* p_W1 = (const float*)d_in[25];  const float* p_b1 = (const float*)d_in[26];
  const float* p_W2 = (const float*)d_in[27];  const float* p_b2 = (const float*)d_in[28];
  const float* p_Wmu = (const float*)d_in[29]; const float* p_bmu = (const float*)d_in[30];
  const float* p_Wls = (const float*)d_in[31]; const float* p_bls = (const float*)d_in[32];
  const float* be_W1 = (const float*)d_in[33]; const float* be_b1 = (const float*)d_in[34];
  const float* be_W2 = (const float*)d_in[35]; const float* be_b2 = (const float*)d_in[36];
  float* out = (float*)d_out;
  char* wsB = (char*)d_ws;
  if ((long long)ws_size < WS_TOTAL) return;  // visible failure if scratch too small

  TrSrcs trs;
  trs.p[0]=iq_W1; trs.p[1]=iq_W2; trs.p[2]=tq_W1; trs.p[3]=tq_W2; trs.p[4]=xw_W1;
  trs.p[5]=xw_W2; trs.p[6]=p_W1; trs.p[7]=p_W2; trs.p[8]=p_Wmu; trs.p[9]=p_Wls; trs.p[10]=be_W1;
  Ptrs ptrs;
  ptrs.bias[0]=xw_b1; ptrs.bias[1]=iq_b1; ptrs.bias[2]=tq_b1; ptrs.bias[3]=p_b1; ptrs.bias[4]=be_b1;
  ptrs.bias[5]=xw_b2; ptrs.bias[6]=iq_b2; ptrs.bias[7]=tq_b2; ptrs.bias[8]=p_b2;
  ptrs.w3[0]=xw_W3; ptrs.w3[1]=iq_W3; ptrs.w3[2]=tq_W3;

  k_route<<<1, 256, 0, stream>>>(wsB, option, out);
  k_tr<<<5312, 256, 0, stream>>>(wsB, trs);
  k_prep<<<9344, 256, 0, stream>>>(wsB, state, action, nstate, option);
  k_gemm<<<dim3(4,272), 256, 0, stream>>>(wsB, OFF_TILEB, ptrs);   // all L1 layers
  k_gemm<<<dim3(4,232), 256, 0, stream>>>(wsB, OFF_TILEC, ptrs);   // all L2 layers (+fused heads)
  k_gemm<<<dim3(1,160), 256, 0, stream>>>(wsB, OFF_TILED, ptrs);   // mu/ls head GEMM, K split x4
  k_bp<<<2048, 256, 0, stream>>>(wsB, noise, p_bmu, p_bls, be_W2, be_b2, out);
  k_td<<<B_SZ/256, 256, 0, stream>>>(wsB, option, reward, done, xw_b3, iq_b3, tq_b3, out);
}

// Round 8
// 468.061 us; speedup vs baseline: 1.9385x; 1.9385x over previous
//
#include <hip/hip_runtime.h>
#include <stdint.h>

#define B_SZ 4096
#define OBS 256
#define ACT 64
#define HID 1024
#define NOPT 8

typedef __attribute__((ext_vector_type(8))) short short8;
typedef __attribute__((ext_vector_type(4))) float floatx4;
typedef __attribute__((ext_vector_type(4))) unsigned int u32x4;

// ---------------- workspace layout (byte offsets) ----------------
constexpr long long OFF_WT_I1 = 0;
constexpr long long OFF_WT_I2 = OFF_WT_I1 + 2LL*1024*256*2;
constexpr long long OFF_WT_T1 = OFF_WT_I2 + 2LL*1024*1024*2;
constexpr long long OFF_WT_T2 = OFF_WT_T1 + 2LL*1024*256*2;
constexpr long long OFF_WT_X1 = OFF_WT_T2 + 2LL*1024*1024*2;
constexpr long long OFF_WT_X2 = OFF_WT_X1 + 2LL*1024*384*2;
constexpr long long OFF_WT_P1 = OFF_WT_X2 + 2LL*1024*1024*2;
constexpr long long OFF_WT_P2 = OFF_WT_P1 + 8LL*1024*256*2;
constexpr long long OFF_WT_ML = OFF_WT_P2 + 8LL*1024*1024*2;
constexpr long long OFF_WT_B1 = OFF_WT_ML + 8LL*128*1024*2;
constexpr long long OFF_XQ    = OFF_WT_B1 + 8LL*1024*256*2;
constexpr long long OFF_NS    = OFF_XQ + 4096LL*384*2;
constexpr long long OFF_AGS   = OFF_NS + 4096LL*256*2;
constexpr long long OFF_AGN   = OFF_AGS + 4224LL*256*2;
constexpr long long OFF_HAX   = OFF_AGN + 4224LL*256*2;
constexpr long long OFF_HAI   = OFF_HAX + 2LL*4096*1024*2;
constexpr long long OFF_HAT   = OFF_HAI + 2LL*4096*1024*2;
constexpr long long OFF_HAP   = OFF_HAT + 2LL*4096*1024*2;
constexpr long long OFF_HAB   = OFF_HAP + 4224LL*1024*2;
constexpr long long OFF_HBP   = OFF_HAB + 4224LL*1024*2;
// partial-sum slices: qi [2z][8sl][4096], qon/qt [2z][8sl][4096][8]
constexpr long long OFF_QI    = OFF_HBP + 4224LL*1024*2;
constexpr long long OFF_QON   = OFF_QI + 2LL*8*4096*4;
constexpr long long OFF_QT    = OFF_QON + 2LL*8*4096*8*4;
// muls partials: [4 kchunk][4224][128] fp32
constexpr long long OFF_MULS  = OFF_QT + 2LL*8*4096*8*4;
constexpr long long MULS_CH   = 4224LL*128*4;
constexpr long long OFF_PERM  = OFF_MULS + 4LL*MULS_CH;
constexpr long long OFF_OPTG  = OFF_PERM + 4096LL*4;
constexpr long long OFF_BP    = OFF_OPTG + ((4224LL*4 + 255) & ~255LL);
constexpr long long OFF_LOGP  = OFF_BP + 4096LL*4;
constexpr long long OFF_TILEB = OFF_LOGP + 4096LL*4;                   // 272*64
constexpr long long OFF_TILEC = OFF_TILEB + 272LL*64;                  // 232*64
constexpr long long OFF_TILED = OFF_TILEC + 232LL*64;                  // 160*64
constexpr long long WS_TOTAL  = OFF_TILED + 160LL*64;

struct Tile {
  long long aOff, wOff, cOff;
  int mStart, mEnd, K, nCols, flags, biasSel, biasOff, redSel, redOff, kLen;
};
struct Ptrs { const float* bias[9]; const float* w3[3]; };
struct TrSrcs { const float* p[11]; };

__device__ __forceinline__ unsigned short f2bf(float x){
  union { float f; unsigned u; } v; v.f = x;
  unsigned r = v.u + 0x7fffu + ((v.u >> 16) & 1u);
  return (unsigned short)(r >> 16);
}
__device__ __forceinline__ float bf2f(unsigned short h){
  union { float f; unsigned u; } v; v.u = ((unsigned)h) << 16; return v.f;
}

// ---------------- layer tables ----------------
__device__ const long long tr_ws[11] = {256*1024,1024*1024,256*1024,1024*1024,328*1024,1024*1024,256*1024,1024*1024,1024*64,1024*64,256*1024};
__device__ const long long tr_ts[11] = {1024*256,1024*1024,1024*256,1024*1024,1024*384,1024*1024,1024*256,1024*1024,128*1024,128*1024,1024*256};
__device__ const long long tr_dst[11] = {OFF_WT_I1,OFF_WT_I2,OFF_WT_T1,OFF_WT_T2,OFF_WT_X1,OFF_WT_X2,OFF_WT_P1,OFF_WT_P2,OFF_WT_ML,OFF_WT_ML+64LL*1024*2,OFF_WT_B1};
__device__ const int t2_cum[12] = {0,128,640,768,1280,1472,1984,2496,4544,4672,4800,5312};
__device__ const int t2_nk[11]  = {4,16,4,16,6,16,4,16,16,16,4};
__device__ const int t2_N[11]   = {1024,1024,1024,1024,1024,1024,1024,1024,64,64,1024};
__device__ const int t2_K[11]   = {256,1024,256,1024,328,1024,256,1024,1024,1024,256};
__device__ const int t2_Kp[11]  = {256,1024,256,1024,384,1024,256,1024,1024,1024,256};

// ---------------- routing + all tile tables ----------------
__global__ void k_route(char* __restrict__ wsB, const int* __restrict__ option,
                        float* __restrict__ out){
  __shared__ int cnt[NOPT], off[NOPT+1], cur[NOPT], ctiles[NOPT], toff[NOPT+1];
  int tid = threadIdx.x;
  int* perm = (int*)(wsB + OFF_PERM);
  int* optg = (int*)(wsB + OFF_OPTG);
  Tile* tb = (Tile*)(wsB + OFF_TILEB);
  Tile* tc = (Tile*)(wsB + OFF_TILEC);
  Tile* tdt = (Tile*)(wsB + OFF_TILED);
  if (tid < NOPT) cnt[tid] = 0;
  __syncthreads();
  for (int b = tid; b < B_SZ; b += 256) atomicAdd(&cnt[option[b]], 1);
  __syncthreads();
  if (tid == 0){
    off[0] = 0; toff[0] = 0;
    for (int o=0;o<NOPT;o++){
      off[o+1] = off[o] + cnt[o];
      ctiles[o] = (cnt[o] + 127) >> 7;
      toff[o+1] = toff[o] + ctiles[o];
      cur[o] = off[o];
    }
    out[0] = 0.f; out[1] = 0.f;
  }
  __syncthreads();
  for (int b = tid; b < B_SZ; b += 256){
    int o = option[b];
    int pos = atomicAdd(&cur[o], 1);
    perm[pos] = b; optg[pos] = o;
  }
  __syncthreads();
  // dense tiles (stage B and C): 6 tasks x 32 m-tiles
  if (tid < 192){
    int task = tid/32, mt = tid%32, z = task&1, net = task>>1;
    int ms = mt*128;
    Tile T{};
    T.mStart = ms; T.mEnd = 4096; T.nCols = 1024; T.flags = 0;
    T.redSel = 0; T.redOff = 0;
    if (net==0){ T.K=384; T.aOff = OFF_XQ + (long long)ms*768; T.wOff = OFF_WT_X1 + (long long)z*786432; T.cOff = OFF_HAX + (long long)z*8388608; T.biasSel=0; }
    else if (net==1){ T.K=256; T.aOff = OFF_NS + (long long)ms*512; T.wOff = OFF_WT_I1 + (long long)z*524288; T.cOff = OFF_HAI + (long long)z*8388608; T.biasSel=1; }
    else { T.K=256; T.aOff = OFF_NS + (long long)ms*512; T.wOff = OFF_WT_T1 + (long long)z*524288; T.cOff = OFF_HAT + (long long)z*8388608; T.biasSel=2; }
    T.biasOff = z*1024; T.kLen = T.K;
    tb[tid] = T;
    Tile C{};
    C.mStart = ms; C.mEnd = 4096; C.K = 1024; C.nCols = 1024; C.kLen = 1024;
    if (net==0){ C.flags=2; C.aOff = OFF_HAX + (long long)z*8388608 + (long long)ms*2048; C.wOff = OFF_WT_X2 + (long long)z*2097152; C.cOff = OFF_QI + (long long)z*131072; C.biasSel=5; C.redSel=0; C.redOff=z*1024; }
    else if (net==1){ C.flags=3; C.aOff = OFF_HAI + (long long)z*8388608 + (long long)ms*2048; C.wOff = OFF_WT_I2 + (long long)z*2097152; C.cOff = OFF_QON + (long long)z*1048576; C.biasSel=6; C.redSel=1; C.redOff=z*8192; }
    else { C.flags=3; C.aOff = OFF_HAT + (long long)z*8388608 + (long long)ms*2048; C.wOff = OFF_WT_T2 + (long long)z*2097152; C.cOff = OFF_QT + (long long)z*1048576; C.biasSel=7; C.redSel=2; C.redOff=z*8192; }
    C.biasOff = z*1024;
    tc[tid] = C;
  }
  // grouped tiles, thread per option
  if (tid < NOPT){
    int o = tid, base = toff[o], gs = off[o], ge = off[o+1];
    for (int t=0; t<ctiles[o]; t++){
      int ms = gs + t*128;
      Tile P{};
      P.mStart=ms; P.mEnd=ge; P.K=256; P.nCols=1024; P.flags=0; P.kLen=256;
      P.aOff = OFF_AGS + (long long)ms*512; P.wOff = OFF_WT_P1 + (long long)o*524288;
      P.cOff = OFF_HAP; P.biasSel=3; P.biasOff=o*1024;
      tb[192 + base + t] = P;
      Tile Bt{};
      Bt.mStart=ms; Bt.mEnd=ge; Bt.K=256; Bt.nCols=1024; Bt.flags=0; Bt.kLen=256;
      Bt.aOff = OFF_AGN + (long long)ms*512; Bt.wOff = OFF_WT_B1 + (long long)o*524288;
      Bt.cOff = OFF_HAB; Bt.biasSel=4; Bt.biasOff=o*1024;
      tb[232 + base + t] = Bt;
      Tile C2{};
      C2.mStart=ms; C2.mEnd=ge; C2.K=1024; C2.nCols=1024; C2.flags=0; C2.kLen=1024;
      C2.aOff = OFF_HAP + (long long)ms*2048; C2.wOff = OFF_WT_P2 + (long long)o*2097152;
      C2.cOff = OFF_HBP; C2.biasSel=8; C2.biasOff=o*1024;
      tc[192 + base + t] = C2;
      // mu/ls head GEMM: K split into 4 chunks of 256, partial outputs
      #pragma unroll
      for (int c=0;c<4;c++){
        Tile M{};
        M.mStart=ms; M.mEnd=ge; M.K=1024; M.nCols=128; M.flags=1; M.kLen=256;
        M.aOff = OFF_HBP + (long long)ms*2048 + c*512;
        M.wOff = OFF_WT_ML + (long long)o*262144 + c*512;
        M.cOff = OFF_MULS + (long long)c*MULS_CH;
        M.biasSel=-1;
        tdt[c*40 + base + t] = M;
      }
    }
  }
  __syncthreads();
  int tT = toff[NOPT];
  for (int s = tT + tid; s < 40; s += 256){
    tb[192+s].kLen = 0; tb[232+s].kLen = 0; tc[192+s].kLen = 0;
    tdt[s].kLen = 0; tdt[40+s].kLen = 0; tdt[80+s].kLen = 0; tdt[120+s].kLen = 0;
  }
}

// ---------------- merged: weight transpose (blocks 0..5311) + prep (blocks 5312..) ----------------
__global__ __launch_bounds__(256)
void k_prep(char* __restrict__ wsB, TrSrcs srcs, const float* __restrict__ state,
            const float* __restrict__ action, const float* __restrict__ nstate,
            const int* __restrict__ option){
  __shared__ float lds[64*68];
  int blk0 = blockIdx.x, tid = threadIdx.x;
  if (blk0 < 5312){
    // ---- transpose 64x64 tile: fp32 [K,N] -> bf16 [N,Kpad] ----
    int id = blk0, j = 0;
    while (id >= t2_cum[j+1]) j++;
    int t = id - t2_cum[j];
    int nk = t2_nk[j], nn = t2_N[j] >> 6;
    int per = nk*nn;
    int z = t / per, r = t % per;
    int kt = r % nk, nt = r / nk;
    int K = t2_K[j], Kp = t2_Kp[j], N = t2_N[j];
    const float* src = srcs.p[j] + (long long)z * tr_ws[j];
    unsigned short* dst = (unsigned short*)(wsB + tr_dst[j]) + (long long)z * tr_ts[j];
    int k0 = kt*64, n0 = nt*64;
    int kl = tid >> 2, nc = tid & 3;
    int krow = k0 + kl;
    const float* s = src + (long long)krow*N + n0 + nc*16;
    #pragma unroll
    for (int i=0;i<4;i++){
      float4 v = (krow < K) ? *(const float4*)(s + i*4) : make_float4(0.f,0.f,0.f,0.f);
      *(float4*)(&lds[kl*68 + nc*16 + i*4]) = v;
    }
    __syncthreads();
    int nl = tid >> 2, kc = tid & 3;
    unsigned int w[8];
    #pragma unroll
    for (int p=0;p<8;p++){
      float a = lds[(kc*16 + 2*p)*68 + nl];
      float b = lds[(kc*16 + 2*p + 1)*68 + nl];
      w[p] = (unsigned)f2bf(a) | ((unsigned)f2bf(b) << 16);
    }
    u32x4 o0 = {w[0],w[1],w[2],w[3]}, o1 = {w[4],w[5],w[6],w[7]};
    char* d = (char*)(dst + (long long)(n0+nl)*Kp + k0 + kc*16);
    *(u32x4*)d = o0; *(u32x4*)(d + 16) = o1;
    return;
  }
  int blk = blk0 - 5312;
  const int* perm = (const int*)(wsB + OFF_PERM);
  if (blk < 4224){
    unsigned short* agS = (unsigned short*)(wsB + OFF_AGS);
    unsigned short* agN = (unsigned short*)(wsB + OFF_AGN);
    long long o = (long long)blk*256 + tid;
    if (blk < 4096){
      long long src = (long long)perm[blk]*256 + tid;
      agS[o] = f2bf(state[src]); agN[o] = f2bf(nstate[src]);
    } else { agS[o] = 0; agN[o] = 0; }
  } else if (blk < 8320){
    int b = blk - 4224;
    unsigned short* xq = (unsigned short*)(wsB + OFF_XQ);
    for (int c = tid; c < 384; c += 256){
      float v;
      if (c < 256) v = state[(long long)b*256 + c];
      else if (c < 320) v = action[(long long)b*64 + (c-256)];
      else if (c < 328) v = (option[b] == (c-320)) ? 1.f : 0.f;
      else v = 0.f;
      xq[(long long)b*384 + c] = f2bf(v);
    }
  } else {
    long long i = (long long)(blk-8320)*1024 + tid;
    unsigned short* nsb = (unsigned short*)(wsB + OFF_NS);
    #pragma unroll
    for (int k=0;k<4;k++){ nsb[i] = f2bf(nstate[i]); i += 256; }
  }
}

// ---------------- unified tiled GEMM body: BM=128, BN=256, BK=64, reg-prefetch ----------------
__device__ __forceinline__ void gemm_body(char* __restrict__ wsB, long long tileOff, const Ptrs& ptrs){
  __shared__ unsigned short As[128*64];
  __shared__ unsigned short Bs[256*64];
  int nx = gridDim.x, T = gridDim.y;
  int id = blockIdx.y*nx + blockIdx.x;
  int xb, yt;
  if ((T & 7) == 0){
    int xcd = id & 7, g = id >> 3;
    xb = g % nx; yt = (g / nx) * 8 + xcd;
  } else { xb = blockIdx.x; yt = blockIdx.y; }
  Tile t = ((const Tile*)(wsB + tileOff))[yt];
  if (t.kLen == 0) return;
  int n0 = xb * 256;
  if (n0 >= t.nCols) return;

  int tid = threadIdx.x;
  int wave = tid >> 6, lane = tid & 63;
  int wm = wave & 1, wn = wave >> 1;
  int quad = lane >> 4, l16 = lane & 15;

  const floatx4 fzero = {0.f,0.f,0.f,0.f};
  floatx4 acc[4][8];
  #pragma unroll
  for (int mi=0;mi<4;mi++)
    #pragma unroll
    for (int ni=0;ni<8;ni++) acc[mi][ni] = fzero;

  long long rowBytes = (long long)t.K*2;
  const char* Abase = wsB + t.aOff;
  const char* Bbase = wsB + t.wOff + (long long)n0*rowBytes;

  int ra0 = tid >> 2, ka0 = (tid & 3) * 16;
  int ra1 = ra0 + 64;
  const char* gA0 = Abase + (long long)ra0*rowBytes + ka0;
  const char* gA1 = Abase + (long long)ra1*rowBytes + ka0;
  const char* gBp[4];
  #pragma unroll
  for (int j=0;j<4;j++){
    int rb = (tid >> 2) + j*64;
    gBp[j] = Bbase + (long long)rb*rowBytes + ka0;
  }

  u32x4 pA[4], pB[8];
  #define PREFETCH(KBB) { \
    long long _kb = (KBB); \
    pA[0] = *(const u32x4*)(gA0 + _kb);      pA[1] = *(const u32x4*)(gA0 + _kb + 64); \
    pA[2] = *(const u32x4*)(gA1 + _kb);      pA[3] = *(const u32x4*)(gA1 + _kb + 64); \
    _Pragma("unroll") \
    for (int j=0;j<4;j++){ \
      pB[2*j]   = *(const u32x4*)(gBp[j] + _kb); \
      pB[2*j+1] = *(const u32x4*)(gBp[j] + _kb + 64); \
    } }
  #define STAGE() { \
    *(u32x4*)((char*)As + tid*16)         = pA[0]; \
    *(u32x4*)((char*)As + 8192 + tid*16)  = pA[1]; \
    *(u32x4*)((char*)As + 4096 + tid*16)  = pA[2]; \
    *(u32x4*)((char*)As + 12288 + tid*16) = pA[3]; \
    _Pragma("unroll") \
    for (int j=0;j<4;j++){ \
      *(u32x4*)((char*)Bs + j*4096 + tid*16)         = pB[2*j]; \
      *(u32x4*)((char*)Bs + 16384 + j*4096 + tid*16) = pB[2*j+1]; \
    } }

  int nkb = t.kLen >> 6;
  PREFETCH(0);
  STAGE();
  __syncthreads();
  for (int kb = 0; kb < nkb; kb++){
    if (kb + 1 < nkb) PREFETCH((long long)(kb+1)*128);
    #pragma unroll
    for (int h=0; h<2; h++){
      short8 af[4], bfr[8];
      #pragma unroll
      for (int mi=0;mi<4;mi++)
        af[mi] = *(const short8*)((const char*)As + h*8192 + (wm*64 + mi*16 + l16)*64 + quad*16);
      #pragma unroll
      for (int ni=0;ni<8;ni++)
        bfr[ni] = *(const short8*)((const char*)Bs + h*16384 + (wn*128 + ni*16 + l16)*64 + quad*16);
      #pragma unroll
      for (int mi=0;mi<4;mi++)
        #pragma unroll
        for (int ni=0;ni<8;ni++)
          acc[mi][ni] = __builtin_amdgcn_mfma_f32_16x16x32_bf16(af[mi], bfr[ni], acc[mi][ni], 0, 0, 0);
    }
    __syncthreads();
    if (kb + 1 < nkb){
      STAGE();
      __syncthreads();
    }
  }
  #undef PREFETCH
  #undef STAGE

  if (t.flags <= 1){
    const float* bz = (t.biasSel >= 0) ? (ptrs.bias[t.biasSel] + t.biasOff) : nullptr;
    #pragma unroll
    for (int ni=0;ni<8;ni++){
      int col = n0 + wn*128 + ni*16 + l16;
      if (col >= t.nCols) continue;
      float bval = bz ? bz[col] : 0.f;
      #pragma unroll
      for (int mi=0;mi<4;mi++){
        int rbase = t.mStart + wm*64 + mi*16 + quad*4;
        floatx4 v = acc[mi][ni];
        #pragma unroll
        for (int r=0;r<4;r++){
          int grow = rbase + r;
          if (grow < t.mEnd){
            float x = v[r] + bval;
            if (t.flags == 0){
              x = fmaxf(x, 0.f);
              ((unsigned short*)(wsB + t.cOff))[(long long)grow*t.nCols + col] = f2bf(x);
            } else {
              ((float*)(wsB + t.cOff))[(long long)grow*t.nCols + col] = x;
            }
          }
        }
      }
    }
  } else {
    // fused head, partial-sum slice per (n-block, wn): no atomics. slices 0..7
    int NC = (t.flags == 2) ? 1 : 8;
    const float* w3 = ptrs.w3[t.redSel] + t.redOff;
    const float* bz = ptrs.bias[t.biasSel] + t.biasOff;
    int sl = xb*2 + wn;  // 0..7
    float* red = (float*)(wsB + t.cOff) + (long long)sl*4096*NC;
    float bv[8]; int colv[8];
    #pragma unroll
    for (int ni=0;ni<8;ni++){ colv[ni] = n0 + wn*128 + ni*16 + l16; bv[ni] = bz[colv[ni]]; }
    #pragma unroll
    for (int mi=0;mi<4;mi++){
      #pragma unroll
      for (int r=0;r<4;r++){
        int row = t.mStart + wm*64 + mi*16 + quad*4 + r;
        float v[8];
        #pragma unroll
        for (int c=0;c<8;c++) v[c] = 0.f;
        #pragma unroll
        for (int ni=0;ni<8;ni++){
          float x = fmaxf(acc[mi][ni][r] + bv[ni], 0.f);
          if (NC == 1) v[0] += x * w3[colv[ni]];
          else {
            #pragma unroll
            for (int c=0;c<8;c++) v[c] += x * w3[colv[ni]*8 + c];
          }
        }
        for (int c=0;c<NC;c++){
          float s = v[c];
          s += __shfl_xor(s,1); s += __shfl_xor(s,2); s += __shfl_xor(s,4); s += __shfl_xor(s,8);
          if (l16 == 0 && row < t.mEnd) red[(long long)row*NC + c] = s;
        }
      }
    }
  }
}

__global__ __launch_bounds__(256, 2)
void k_gemm_l1(char* __restrict__ wsB, long long tileOff, Ptrs ptrs){ gemm_body(wsB, tileOff, ptrs); }
__global__ __launch_bounds__(256, 2)
void k_gemm_l2(char* __restrict__ wsB, long long tileOff, Ptrs ptrs){ gemm_body(wsB, tileOff, ptrs); }
__global__ __launch_bounds__(256, 2)
void k_gemm_hd(char* __restrict__ wsB, long long tileOff, Ptrs ptrs){ gemm_body(wsB, tileOff, ptrs); }

// ---------------- fused beta head + policy epilogue (4 jobs/block) ----------------
__global__ void k_bp(char* __restrict__ wsB, const float* __restrict__ noise,
                     const float* __restrict__ bmu, const float* __restrict__ bls,
                     const float* __restrict__ beW2, const float* __restrict__ beb2,
                     float* __restrict__ out){
  int job = blockIdx.x*4 + (threadIdx.x >> 6);
  int lane = threadIdx.x & 63;
  const int* perm = (const int*)(wsB + OFF_PERM);
  const int* optg = (const int*)(wsB + OFF_OPTG);
  if (job < B_SZ){
    int i = job, o = optg[i], b = perm[i];
    const float* muls = (const float*)(wsB + OFF_MULS);
    float* logp = (float*)(wsB + OFF_LOGP);
    float mu = bmu[o*ACT + lane];
    float ls = bls[o*ACT + lane];
    #pragma unroll
    for (int c=0;c<4;c++){
      mu += muls[(long long)c*(MULS_CH/4) + (long long)i*128 + lane];
      ls += muls[(long long)c*(MULS_CH/4) + (long long)i*128 + 64 + lane];
    }
    ls = fminf(fmaxf(ls, -20.f), 2.f);
    float nv = noise[(long long)b*ACT + lane];
    float pre = mu + expf(ls)*nv;
    out[2 + (long long)b*ACT + lane] = tanhf(pre);
    float xx = -2.f*pre;
    float sp = fmaxf(xx, 0.f) + log1pf(expf(-fabsf(xx)));
    const float LOG2PI = 1.8378770664093453f;
    const float LN2 = 0.6931471805599453f;
    float lp = -0.5f*nv*nv - ls - 0.5f*LOG2PI - 2.f*(LN2 - pre - sp);
    for (int s=32;s;s>>=1) lp += __shfl_xor(lp, s);
    if (lane == 0){ out[2 + (long long)B_SZ*ACT + b] = lp; logp[b] = lp; }
  } else {
    int i = job - B_SZ, o = optg[i], b = perm[i];
    const char* hrow = wsB + OFF_HAB + (long long)i*2048;
    const float* w = beW2 + (long long)o*HID;
    float* bp = (float*)(wsB + OFF_BP);
    short8 v0 = *(const short8*)(hrow + lane*16);
    short8 v1 = *(const short8*)(hrow + 1024 + lane*16);
    float acc = 0.f;
    #pragma unroll
    for (int e=0;e<8;e++){
      acc += bf2f((unsigned short)v0[e]) * w[lane*8 + e];
      acc += bf2f((unsigned short)v1[e]) * w[512 + lane*8 + e];
    }
    for (int s=32;s;s>>=1) acc += __shfl_xor(acc, s);
    if (lane == 0){
      float v = 1.f/(1.f + expf(-(acc + beb2[o])));
      out[2 + (long long)B_SZ*ACT + B_SZ + b] = v; bp[b] = v;
    }
  }
}

// ---------------- TD target + losses (reduces 8 partial slices) ----------------
__global__ void k_td(const char* __restrict__ wsB, const int* __restrict__ option,
                     const float* __restrict__ reward, const float* __restrict__ done,
                     const float* __restrict__ xb3, const float* __restrict__ ib3,
                     const float* __restrict__ tb3, float* __restrict__ out){
  int b = blockIdx.x*256 + threadIdx.x;
  const float* qiP  = (const float*)(wsB + OFF_QI);
  const float* qonP = (const float*)(wsB + OFF_QON);
  const float* qtP  = (const float*)(wsB + OFF_QT);
  const float* bp   = (const float*)(wsB + OFF_BP);
  const float* logp = (const float*)(wsB + OFF_LOGP);
  float q1 = xb3[0], q2 = xb3[1];
  #pragma unroll
  for (int sl=0; sl<8; sl++){
    q1 += qiP[sl*4096 + b];
    q2 += qiP[32768 + sl*4096 + b];
  }
  float qons[2][8], qts[2][8];
  #pragma unroll
  for (int z=0;z<2;z++)
    #pragma unroll
    for (int o=0;o<8;o++){ qons[z][o] = ib3[z*8+o]; qts[z][o] = tb3[z*8+o]; }
  for (int z=0;z<2;z++){
    for (int sl=0; sl<8; sl++){
      long long base = ((long long)(z*8 + sl)*4096 + b)*8;
      #pragma unroll
      for (int o=0;o<8;o++){ qons[z][o] += qonP[base+o]; qts[z][o] += qtP[base+o]; }
    }
  }
  float qitv[NOPT];
  #pragma unroll
  for (int o=0;o<NOPT;o++) qitv[o] = fminf(qts[0][o], qts[1][o]);
  float qcur = qitv[option[b]];
  float best = -1e30f; int bo = 0;
  #pragma unroll
  for (int o=0;o<NOPT;o++){
    float v = fminf(qons[0][o], qons[1][o]);
    if (v > best){ best = v; bo = o; }
  }
  float qnext = qitv[bo];
  float bpv = bp[b];
  float backup = reward[b] + 0.99f*(1.f - done[b])*((1.f - bpv)*qcur + bpv*qnext);
  float d1 = q1 - backup, d2 = q2 - backup;
  float tq = d1*d1 + d2*d2;
  float qpi = fminf(q1, q2);
  float tp = 0.2f*logp[b] - qpi;
  for (int s=32;s;s>>=1){ tq += __shfl_xor(tq, s); tp += __shfl_xor(tp, s); }
  __shared__ float sq[4], sp2[4];
  int wave = threadIdx.x>>6, lane = threadIdx.x&63;
  if (lane==0){ sq[wave]=tq; sp2[wave]=tp; }
  __syncthreads();
  if (threadIdx.x==0){
    atomicAdd(&out[0], (sq[0]+sq[1]+sq[2]+sq[3])/(float)B_SZ);
    atomicAdd(&out[1], (sp2[0]+sp2[1]+sp2[2]+sp2[3])/(float)B_SZ);
  }
}

extern "C" void kernel_launch(void* const* d_in, const int* in_sizes, int n_in,
                              void* d_out, int out_size, void* d_ws, size_t ws_size,
                              hipStream_t stream){
  const float* state  = (const float*)d_in[0];
  const float* action = (const float*)d_in[1];
  const float* nstate = (const float*)d_in[2];
  const float* reward = (const float*)d_in[3];
  const float* done   = (const float*)d_in[4];
  const float* noise  = (const float*)d_in[5];
  const int*   option = (const int*)d_in[6];
  const float* iq_W1 = (const float*)d_in[7];  const float* iq_b1 = (const float*)d_in[8];
  const float* iq_W2 = (const float*)d_in[9];  const float* iq_b2 = (const float*)d_in[10];
  const float* iq_W3 = (const float*)d_in[11]; const float* iq_b3 = (const float*)d_in[12];
  const float* tq_W1 = (const float*)d_in[13]; const float* tq_b1 = (const float*)d_in[14];
  const float* tq_W2 = (const float*)d_in[15]; const float* tq_b2 = (const float*)d_in[16];
  const float* tq_W3 = (const float*)d_in[17]; const float* tq_b3 = (const float*)d_in[18];
  const float* xw_W1 = (const float*)d_in[19]; const float* xw_b1 = (const float*)d_in[20];
  const float* xw_W2 = (const float*)d_in[21]; const float* xw_b2 = (const float*)d_in[22];
  const float* xw_W3 = (const float*)d_in[23]; const float* xw_b3 = (const float*)d_in[24];
  const float* p_W1 = (const float*)d_in[25];  const float* p_b1 = (const float*)d_in[26];
  const float* p_W2 = (const float*)d_in[27];  const float* p_b2 = (const float*)d_in[28];
  const float* p_Wmu = (const float*)d_in[29]; const float* p_bmu = (const float*)d_in[30];
  const float* p_Wls = (const float*)d_in[31]; const float* p_bls = (const float*)d_in[32];
  const float* be_W1 = (const float*)d_in[33]; const float* be_b1 = (const float*)d_in[34];
  const float* be_W2 = (const float*)d_in[35]; const float* be_b2 = (const float*)d_in[36];
  float* out = (float*)d_out;
  char* wsB = (char*)d_ws;
  if ((long long)ws_size < WS_TOTAL) return;  // visible failure if scratch too small

  TrSrcs trs;
  trs.p[0]=iq_W1; trs.p[1]=iq_W2; trs.p[2]=tq_W1; trs.p[3]=tq_W2; trs.p[4]=xw_W1;
  trs.p[5]=xw_W2; trs.p[6]=p_W1; trs.p[7]=p_W2; trs.p[8]=p_Wmu; trs.p[9]=p_Wls; trs.p[10]=be_W1;
  Ptrs ptrs;
  ptrs.bias[0]=xw_b1; ptrs.bias[1]=iq_b1; ptrs.bias[2]=tq_b1; ptrs.bias[3]=p_b1; ptrs.bias[4]=be_b1;
  ptrs.bias[5]=xw_b2; ptrs.bias[6]=iq_b2; ptrs.bias[7]=tq_b2; ptrs.bias[8]=p_b2;
  ptrs.w3[0]=xw_W3; ptrs.w3[1]=iq_W3; ptrs.w3[2]=tq_W3;

  k_route<<<1, 256, 0, stream>>>(wsB, option, out);
  k_prep<<<5312 + 9344, 256, 0, stream>>>(wsB, trs, state, action, nstate, option);
  k_gemm_l1<<<dim3(4,272), 256, 0, stream>>>(wsB, OFF_TILEB, ptrs);  // all L1 layers
  k_gemm_l2<<<dim3(4,232), 256, 0, stream>>>(wsB, OFF_TILEC, ptrs);  // all L2 layers (+fused heads)
  k_gemm_hd<<<dim3(1,160), 256, 0, stream>>>(wsB, OFF_TILED, ptrs);  // mu/ls head GEMM, K split x4
  k_bp<<<2048, 256, 0, stream>>>(wsB, noise, p_bmu, p_bls, be_W2, be_b2, out);
  k_td<<<B_SZ/256, 256, 0, stream>>>(wsB, option, reward, done, xw_b3, iq_b3, tq_b3, out);
}